// Round 1
// baseline (3184.185 us; speedup 1.0000x reference)
//
#include <hip/hip_runtime.h>
#include <cstdint>
#include <cfloat>
#include <cstddef>

// ---------------- problem constants ----------------
constexpr int BATCH   = 2;
constexpr int V       = 12000;
constexpr int VP      = V + 1;        // 12001 (incl. dummy vertex)
constexpr int M_ROWS  = BATCH * VP;   // 24002
constexpr int L_SP    = 16;

#define TILE 64
#define BK   16
#define AS_STRIDE 68   // 64 + 4 pad: keeps 16B alignment, spreads banks

// ---------------------------------------------------------------------------
// Generic 64x64 register-tiled fp32 GEMM.
//   GATHER=true : A row m=(b,v) is concat over l of feat[b, idx[v,l], 0:C]
//   GATHER=false: A is [BATCH, A_V, KA]; rows with v >= A_V read as zero
// Epilogue: out = maybe_relu(acc + bias + res); rows v==VP-1 forced to 0 when
// mask!=0 (the zero_padding multiply in the reference).
// ---------------------------------------------------------------------------
template<bool GATHER, bool AVEC>
__global__ __launch_bounds__(256)
void gemm_k(const float* __restrict__ A, const float* __restrict__ W,
            const float* __restrict__ bias, const float* __restrict__ res,
            const int* __restrict__ idx, float* __restrict__ out,
            int M, int N, int K, int C, int A_V, int KA,
            int relu, int mask)
{
    __shared__ float As[BK][AS_STRIDE];
    __shared__ float Bs[BK][TILE];

    const int tid = threadIdx.x;
    const int tx  = tid & 15;          // 0..15 -> 4 output cols
    const int ty  = tid >> 4;          // 0..15 -> 4 output rows
    const int bm  = blockIdx.x;
    const int bn  = blockIdx.y;

    // A-tile load mapping: 64 rows x 16 k, one float4 per thread
    const int ar = tid >> 2;           // 0..63
    const int ac = (tid & 3) << 2;     // 0,4,8,12
    const int am = bm * TILE + ar;

    // B-tile load mapping: 16 k x 64 n, one float4 per thread
    const int br = tid >> 4;           // 0..15
    const int bc = (tid & 15) << 2;    // 0..60
    const int wn = bn * TILE + bc;

    float acc[4][4] = {};

    const int nk = (K + BK - 1) / BK;
    for (int t = 0; t < nk; ++t) {
        const int k0 = t * BK;

        // ---- load A tile ----
        float a0 = 0.f, a1 = 0.f, a2 = 0.f, a3 = 0.f;
        if (am < M) {
            const int b = am / VP;
            const int v = am - b * VP;
            if (GATHER) {
                const int l    = k0 / C;           // BK divides C -> tile within one l
                const int coff = k0 - l * C + ac;
                const int j    = idx[v * L_SP + l];
                const float4 av = *(const float4*)(A + ((size_t)(b * VP + j)) * C + coff);
                a0 = av.x; a1 = av.y; a2 = av.z; a3 = av.w;
            } else {
                if (v < A_V) {
                    const float* ap = A + ((size_t)b * A_V + v) * KA + k0 + ac;
                    if (AVEC) {
                        const float4 av = *(const float4*)ap;
                        a0 = av.x; a1 = av.y; a2 = av.z; a3 = av.w;
                    } else {
                        const int kb = k0 + ac;
                        if (kb + 0 < K) a0 = ap[0];
                        if (kb + 1 < K) a1 = ap[1];
                        if (kb + 2 < K) a2 = ap[2];
                        if (kb + 3 < K) a3 = ap[3];
                    }
                }
            }
        }
        As[ac + 0][ar] = a0;
        As[ac + 1][ar] = a1;
        As[ac + 2][ar] = a2;
        As[ac + 3][ar] = a3;

        // ---- load B tile ----
        float4 wv = {0.f, 0.f, 0.f, 0.f};
        const int k = k0 + br;
        if (k < K) wv = *(const float4*)(W + (size_t)k * N + wn);
        *(float4*)&Bs[br][bc] = wv;

        __syncthreads();

        // ---- compute ----
#pragma unroll
        for (int kk = 0; kk < BK; ++kk) {
            const float4 av = *(const float4*)&As[kk][ty << 2];
            const float4 bv = *(const float4*)&Bs[kk][tx << 2];
            const float ax[4] = {av.x, av.y, av.z, av.w};
            const float bx[4] = {bv.x, bv.y, bv.z, bv.w};
#pragma unroll
            for (int i = 0; i < 4; ++i)
#pragma unroll
                for (int j = 0; j < 4; ++j)
                    acc[i][j] += ax[i] * bx[j];
        }
        __syncthreads();
    }

    // ---- epilogue ----
    const int n0 = bn * TILE + (tx << 2);
#pragma unroll
    for (int i = 0; i < 4; ++i) {
        const int m = bm * TILE + (ty << 2) + i;
        if (m >= M) continue;
        const int v = m % VP;
        const bool dead = mask && (v == VP - 1);
#pragma unroll
        for (int j = 0; j < 4; ++j) {
            const int n = n0 + j;
            float val = acc[i][j];
            if (bias) val += bias[n];
            if (res)  val += res[(size_t)m * N + n];
            if (relu) val = fmaxf(val, 0.f);
            out[(size_t)m * N + n] = dead ? 0.f : val;
        }
    }
}

// ---------------------------------------------------------------------------
// Masked global max-pool over vertices 0..V-1 (dummy vertex excluded).
// fs: [BATCH, VP, 128] -> gfs: [BATCH, 128]
// ---------------------------------------------------------------------------
__global__ void maxpool_k(const float* __restrict__ fs, float* __restrict__ gfs)
{
    const int b    = blockIdx.x;
    const int c    = threadIdx.x & 127;
    const int half = threadIdx.x >> 7;
    const int v0   = half * (V / 2);
    const int v1   = v0 + (V / 2);

    float m = -FLT_MAX;
    const float* p = fs + ((size_t)b * VP + v0) * 128 + c;
    for (int v = v0; v < v1; ++v) { m = fmaxf(m, *p); p += 128; }

    __shared__ float red[256];
    red[threadIdx.x] = m;
    __syncthreads();
    if (half == 0) gfs[b * 128 + c] = fmaxf(red[c], red[128 + c]);
}

// ---------------------------------------------------------------------------
// h512[b,v] = [pfs(256) | fs(128) | broadcast gfs(128)*zp]
// ---------------------------------------------------------------------------
__global__ void concat_k(const float* __restrict__ pfs, const float* __restrict__ fs,
                         const float* __restrict__ gfs, float* __restrict__ h)
{
    const size_t i = (size_t)blockIdx.x * blockDim.x + threadIdx.x;
    const size_t total = (size_t)M_ROWS * 512;
    if (i >= total) return;
    const int    n   = (int)(i & 511);
    const size_t row = i >> 9;
    const int    b   = (int)(row / VP);
    const int    v   = (int)(row - (size_t)b * VP);
    float val;
    if (n < 256)      val = pfs[row * 256 + n];
    else if (n < 384) val = fs[row * 128 + (n - 256)];
    else              val = (v == VP - 1) ? 0.f : gfs[b * 128 + (n - 384)];
    h[i] = val;
}

// ---------------------------------------------------------------------------
// Final tiny layer: out[b,v,0:3] = h128[b,v,:] @ Wo3 + bo3, v < V only.
// ---------------------------------------------------------------------------
__global__ void final_k(const float* __restrict__ h, const float* __restrict__ Wo3,
                        const float* __restrict__ bo3, float* __restrict__ out)
{
    __shared__ float w[384];
    __shared__ float b3[3];
    for (int t = threadIdx.x; t < 384; t += 256) w[t] = Wo3[t];
    if (threadIdx.x < 3) b3[threadIdx.x] = bo3[threadIdx.x];
    __syncthreads();

    const int gid = blockIdx.x * 256 + threadIdx.x;
    if (gid >= BATCH * V) return;
    const int b = gid / V;
    const int v = gid - b * V;
    const float* hr = h + ((size_t)b * VP + v) * 128;

    float o0 = b3[0], o1 = b3[1], o2 = b3[2];
#pragma unroll 4
    for (int c = 0; c < 128; ++c) {
        const float hv = hr[c];
        o0 += hv * w[c * 3 + 0];
        o1 += hv * w[c * 3 + 1];
        o2 += hv * w[c * 3 + 2];
    }
    out[(size_t)gid * 3 + 0] = o0;
    out[(size_t)gid * 3 + 1] = o1;
    out[(size_t)gid * 3 + 2] = o2;
}

// ---------------------------------------------------------------------------
extern "C" void kernel_launch(void* const* d_in, const int* in_sizes, int n_in,
                              void* d_out, int out_size, void* d_ws, size_t ws_size,
                              hipStream_t stream)
{
    const float* x       = (const float*)d_in[0];   // [B,V,479]
    const int*   sidx    = (const int*)  d_in[1];   // [VP,16]
    const float* W_point = (const float*)d_in[2];   // [479,256]
    const float* res1_W  = (const float*)d_in[3];   // [2,4096,256]
    const float* res1_b  = (const float*)d_in[4];   // [2,256]
    const float* W_mid   = (const float*)d_in[5];   // [256,128]
    const float* ress_W  = (const float*)d_in[6];   // [3,2,2048,128]
    const float* ress_b  = (const float*)d_in[7];   // [3,2,128]
    const float* Wo1     = (const float*)d_in[8];   // [512,256]
    const float* bo1     = (const float*)d_in[9];
    const float* Wo2     = (const float*)d_in[10];  // [256,128]
    const float* bo2     = (const float*)d_in[11];
    const float* Wo3     = (const float*)d_in[12];  // [128,3]
    const float* bo3     = (const float*)d_in[13];
    float* out = (float*)d_out;

    // ---- workspace carving (with reuse; ~111 MB total) ----
    float* ws = (float*)d_ws;
    size_t off = 0;
    auto alloc = [&](size_t n) { float* p = ws + off; off += n; return p; };
    float* pfs  = alloc((size_t)M_ROWS * 256);   // live until concat
    float* bufA = alloc((size_t)M_ROWS * 256);   // h1
    float* bufB = alloc((size_t)M_ROWS * 256);   // r1
    float* fsA  = alloc((size_t)M_ROWS * 128);
    float* fsB  = alloc((size_t)M_ROWS * 128);
    float* tmp  = alloc((size_t)M_ROWS * 128);
    float* gfs  = alloc(256);
    // reuse: h512 over bufA+bufB (12,289,024 floats, contiguous);
    //        h256 over fsA+fsB; h128 over tmp
    float* h512 = bufA;
    float* h256 = fsA;
    float* h128 = tmp;

    const dim3 blk(256);
    const int mt = (M_ROWS + TILE - 1) / TILE;   // 376

    // 1. pointMLP: pfs = relu(x @ W_point), dummy row zeroed  (K=479, scalar A loads)
    gemm_k<false, false><<<dim3(mt, 4), blk, 0, stream>>>(
        x, W_point, nullptr, nullptr, nullptr, pfs,
        M_ROWS, 256, 479, 0, V, 479, /*relu*/1, /*mask*/1);

    // 2. res1 conv a: h1 = relu(gather(pfs) @ Wa + ba) * zp
    gemm_k<true, true><<<dim3(mt, 4), blk, 0, stream>>>(
        pfs, res1_W, res1_b, nullptr, sidx, bufA,
        M_ROWS, 256, 4096, 256, VP, 0, 1, 1);

    // 3. res1 conv b + residual: r1 = relu(gather(h1) @ Wb + bb + pfs) * zp
    gemm_k<true, true><<<dim3(mt, 4), blk, 0, stream>>>(
        bufA, res1_W + (size_t)4096 * 256, res1_b + 256, pfs, sidx, bufB,
        M_ROWS, 256, 4096, 256, VP, 0, 1, 1);

    // 4. midDown: fsA = (r1 @ W_mid) * zp   (no bias, no relu)
    gemm_k<false, true><<<dim3(mt, 2), blk, 0, stream>>>(
        bufB, W_mid, nullptr, nullptr, nullptr, fsA,
        M_ROWS, 128, 256, 0, VP, 256, 0, 1);

    // 5. masked global max-pool
    maxpool_k<<<BATCH, 256, 0, stream>>>(fsA, gfs);

    // 6. three 128-ch residual spiral blocks (ping-pong fsA/fsB via tmp)
    const float* cur = fsA;
    float* nxt = fsB;
    for (int i = 0; i < 3; ++i) {
        const float* Wa = ress_W + ((size_t)(2 * i + 0)) * 2048 * 128;
        const float* Wb = ress_W + ((size_t)(2 * i + 1)) * 2048 * 128;
        const float* ba = ress_b + (2 * i + 0) * 128;
        const float* bb = ress_b + (2 * i + 1) * 128;
        gemm_k<true, true><<<dim3(mt, 2), blk, 0, stream>>>(
            cur, Wa, ba, nullptr, sidx, tmp,
            M_ROWS, 128, 2048, 128, VP, 0, 1, 1);
        gemm_k<true, true><<<dim3(mt, 2), blk, 0, stream>>>(
            tmp, Wb, bb, cur, sidx, nxt,
            M_ROWS, 128, 2048, 128, VP, 0, 1, 1);
        float* t = (float*)cur; cur = nxt; nxt = t;
    }
    // after 3 iterations cur == fsB

    // 7. concat -> h512 (overwrites bufA+bufB, both dead now)
    {
        const size_t total = (size_t)M_ROWS * 512;
        concat_k<<<(unsigned)((total + 255) / 256), blk, 0, stream>>>(pfs, cur, gfs, h512);
    }

    // 8. out MLP 1: h256 = relu(h512 @ Wo1 + bo1)   (writes fsA+fsB region, dead now)
    gemm_k<false, true><<<dim3(mt, 4), blk, 0, stream>>>(
        h512, Wo1, bo1, nullptr, nullptr, h256,
        M_ROWS, 256, 512, 0, VP, 512, 1, 0);

    // 9. out MLP 2: h128 = relu(h256 @ Wo2 + bo2)   (writes tmp region, dead now)
    gemm_k<false, true><<<dim3(mt, 2), blk, 0, stream>>>(
        h256, Wo2, bo2, nullptr, nullptr, h128,
        M_ROWS, 128, 256, 0, VP, 256, 1, 0);

    // 10. final 128->3 + drop dummy vertex
    final_k<<<(BATCH * V + 255) / 256, blk, 0, stream>>>(h128, Wo3, bo3, out);
}

// Round 4
// 873.109 us; speedup vs baseline: 3.6469x; 3.6469x over previous
//
#include <hip/hip_runtime.h>
#include <cstdint>
#include <cfloat>
#include <cstddef>

// ---------------- problem constants ----------------
constexpr int BATCH  = 2;
constexpr int V      = 12000;
constexpr int VP     = V + 1;        // 12001
constexpr int M_ROWS = BATCH * VP;   // 24002
constexpr int L_SP   = 16;

typedef _Float16 half_t;
typedef _Float16 half8 __attribute__((ext_vector_type(8)));
typedef float floatx4 __attribute__((ext_vector_type(4)));

// async global->LDS, 16B per lane (global_load_lds_dwordx4)
__device__ __forceinline__ void async_cp16(const void* g, void* l) {
    __builtin_amdgcn_global_load_lds(
        (const __attribute__((address_space(1))) unsigned int*)g,
        (__attribute__((address_space(3))) unsigned int*)l, 16, 0, 0);
}

// ---------------------------------------------------------------------------
// f16 MFMA GEMM, m97 structure: 128x128 tile, BK=32, 256 thr / 4 waves,
// each wave a 64x64 quadrant as 4x4 grid of v_mfma_f32_16x16x32_f16.
//   GATHER: A row m=(b,v) = concat_l act[b*VP + idx[v][l], 0:C], C=2^lgC
//   else  : A is [M][KA] fp16 row-major
// Wt is [N][K] fp16 (pre-transposed weights). Epilogue: fp32 acc + bias(f32)
// + res(f16), optional relu, rows v==VP-1 zeroed when mask. Output fp16.
// Requires: N % 128 == 0, K % 32 == 0, (GATHER) 32 | C.
// ---------------------------------------------------------------------------
template<bool GATHER>
__global__ __launch_bounds__(256, 2)
void gemm_mfma(const half_t* __restrict__ A, const half_t* __restrict__ Wt,
               const float* __restrict__ bias, const half_t* __restrict__ res,
               const int* __restrict__ idx, half_t* __restrict__ out,
               int M, int N, int K, int lgC, int KA, int relu, int mask)
{
    __shared__ half_t As[128 * 32];
    __shared__ half_t Bs[128 * 32];

    const int tid  = threadIdx.x;
    const int lane = tid & 63;
    const int w    = tid >> 6;
    const int bm   = blockIdx.x, bn = blockIdx.y;

    // staging: wave w stages tile rows [w*32, w*32+32); 4 lanes x 16B per row
    const int sr0 = (w << 5) + (lane >> 2);
    const int sr1 = sr0 + 16;
    const int sb  = (lane & 3) << 3;          // half offset within 64B row slice

    int m0 = bm * 128 + sr0; if (m0 >= M) m0 = M - 1;
    int m1 = bm * 128 + sr1; if (m1 >= M) m1 = M - 1;
    const int b0 = m0 / VP, v0 = m0 - b0 * VP;
    const int b1 = m1 / VP, v1 = m1 - b1 * VP;

    const half_t* a0 = nullptr;
    const half_t* a1 = nullptr;
    if (!GATHER) {
        a0 = A + (size_t)m0 * KA + sb;
        a1 = A + (size_t)m1 * KA + sb;
    }
    const half_t* w0 = Wt + (size_t)(bn * 128 + sr0) * K + sb;
    const half_t* w1 = Wt + (size_t)(bn * 128 + sr1) * K + sb;

    half_t* lA0 = &As[sr0 * 32 + sb];   // lane-contiguous: wave base + lane*16B
    half_t* lA1 = &As[sr1 * 32 + sb];
    half_t* lB0 = &Bs[sr0 * 32 + sb];
    half_t* lB1 = &Bs[sr1 * 32 + sb];

    // compute mapping: wave quadrant + fragment addressing
    const int wm = (w >> 1) << 6;
    const int wn = (w & 1) << 6;
    const int fr = lane & 15;            // A row / B col within 16-tile
    const int qk = (lane >> 4) << 3;     // k offset = quad*8

    floatx4 acc[4][4] = {};

    int curl = -1;
    const half_t* g0 = nullptr;
    const half_t* g1 = nullptr;
    const int Cm1 = (1 << lgC) - 1;

    const int nk = K >> 5;
    for (int t = 0; t < nk; ++t) {
        const int k0 = t << 5;
        if (GATHER) {
            const int l = k0 >> lgC;     // wave-uniform
            if (l != curl) {
                curl = l;
                const int j0 = idx[(v0 << 4) + l];
                const int j1 = idx[(v1 << 4) + l];
                g0 = A + (((size_t)(b0 * VP + j0)) << lgC) + sb;
                g1 = A + (((size_t)(b1 * VP + j1)) << lgC) + sb;
            }
            const int koff = k0 & Cm1;
            async_cp16(g0 + koff, lA0);
            async_cp16(g1 + koff, lA1);
        } else {
            async_cp16(a0 + k0, lA0);
            async_cp16(a1 + k0, lA1);
        }
        async_cp16(w0 + k0, lB0);
        async_cp16(w1 + k0, lB1);
        __syncthreads();   // drains vmcnt before barrier => staging visible

        half8 af[4], bf[4];
#pragma unroll
        for (int i = 0; i < 4; ++i)
            af[i] = *(const half8*)&As[(wm + (i << 4) + fr) * 32 + qk];
#pragma unroll
        for (int j = 0; j < 4; ++j)
            bf[j] = *(const half8*)&Bs[(wn + (j << 4) + fr) * 32 + qk];
#pragma unroll
        for (int i = 0; i < 4; ++i)
#pragma unroll
            for (int j = 0; j < 4; ++j)
                acc[i][j] = __builtin_amdgcn_mfma_f32_16x16x32_f16(af[i], bf[j], acc[i][j], 0, 0, 0);
        __syncthreads();
    }

    // epilogue: C/D layout col=lane&15, row=(lane>>4)*4+reg
    const int er = (lane >> 4) << 2;
#pragma unroll
    for (int i = 0; i < 4; ++i) {
#pragma unroll
        for (int j = 0; j < 4; ++j) {
            const int n = bn * 128 + wn + (j << 4) + fr;
            const floatx4 a = acc[i][j];
#pragma unroll
            for (int r = 0; r < 4; ++r) {
                const int m = bm * 128 + wm + (i << 4) + er + r;
                if (m >= M) continue;
                float val = a[r];
                if (bias) val += bias[n];
                if (res)  val += (float)res[(size_t)m * N + n];
                if (relu) val = fmaxf(val, 0.f);
                const int vv = m - (m / VP) * VP;
                if (mask && vv == VP - 1) val = 0.f;
                out[(size_t)m * N + n] = (half_t)val;
            }
        }
    }
}

// ---------------------------------------------------------------------------
// weight convert + transpose fp32 [z][K][N] -> fp16 [z][N][Kpad] (zero-pad K)
// grid (ceil(Kpad/32), ceil(N/32), z), block 256 (32x8)
// ---------------------------------------------------------------------------
__global__ void wcvt(const float* __restrict__ in, half_t* __restrict__ out,
                     int K, int N, int Kpad)
{
    __shared__ float t[32][33];
    const size_t ioff = (size_t)blockIdx.z * K * N;
    const size_t ooff = (size_t)blockIdx.z * N * Kpad;
    const int k0 = blockIdx.x * 32, n0 = blockIdx.y * 32;
    const int tx = threadIdx.x & 31, ty = threadIdx.x >> 5;
#pragma unroll
    for (int r = 0; r < 4; ++r) {
        const int k = k0 + ty + r * 8;
        t[ty + r * 8][tx] = (k < K && n0 + tx < N) ? in[ioff + (size_t)k * N + n0 + tx] : 0.f;
    }
    __syncthreads();
#pragma unroll
    for (int r = 0; r < 4; ++r) {
        const int n = n0 + ty + r * 8;
        const int k = k0 + tx;
        if (n < N && k < Kpad) out[ooff + (size_t)n * Kpad + k] = (half_t)t[tx][ty + r * 8];
    }
}

// x [B][V][479] fp32 -> xh [B*VP][480] fp16, pad col 479 and dummy rows = 0
__global__ void cvt_x(const float* __restrict__ x, half_t* __restrict__ xh)
{
    const int m = blockIdx.x;
    const int b = m / VP, v = m - b * VP;
    for (int k = threadIdx.x; k < 480; k += 256) {
        float val = (v < V && k < 479) ? x[((size_t)b * V + v) * 479 + k] : 0.f;
        xh[(size_t)m * 480 + k] = (half_t)val;
    }
}

// masked global max-pool, 2 stages. fs fp16 [B*VP][128]
__global__ void maxpool1(const half_t* __restrict__ fs, float* __restrict__ pmax)
{
    const int b = blockIdx.x, chunk = blockIdx.y;   // grid (2,32), block 128
    const int c = threadIdx.x;
    const int v0 = chunk * (V / 32);
    float m = -FLT_MAX;
    const half_t* p = fs + ((size_t)b * VP + v0) * 128 + c;
    for (int v = 0; v < V / 32; ++v) { m = fmaxf(m, (float)*p); p += 128; }
    pmax[((size_t)b * 32 + chunk) * 128 + c] = m;
}
__global__ void maxpool2(const float* __restrict__ pmax, half_t* __restrict__ gfs)
{
    const int b = blockIdx.x, c = threadIdx.x;      // grid 2, block 128
    float m = -FLT_MAX;
    for (int i = 0; i < 32; ++i) m = fmaxf(m, pmax[((size_t)b * 32 + i) * 128 + c]);
    gfs[b * 128 + c] = (half_t)m;
}

// h512[m] = [pfs(256) | fs(128) | gfs(128)*zp]  (fp16)
__global__ void concat_k(const half_t* __restrict__ pfs, const half_t* __restrict__ fs,
                         const half_t* __restrict__ gfs, half_t* __restrict__ h)
{
    const size_t i = (size_t)blockIdx.x * 256 + threadIdx.x;
    if (i >= (size_t)M_ROWS * 512) return;
    const int    n   = (int)(i & 511);
    const size_t row = i >> 9;
    const int    b   = (int)(row / VP);
    const int    v   = (int)(row - (size_t)b * VP);
    half_t val;
    if (n < 256)      val = pfs[row * 256 + n];
    else if (n < 384) val = fs[row * 128 + (n - 256)];
    else              val = (v == VP - 1) ? (half_t)0.f : gfs[b * 128 + (n - 384)];
    h[i] = val;
}

// final 128->3 (fp32 weights for accuracy), drop dummy vertex
__global__ void final_k(const half_t* __restrict__ h, const float* __restrict__ Wo3,
                        const float* __restrict__ bo3, float* __restrict__ out)
{
    __shared__ float wsm[384];
    __shared__ float b3[3];
    for (int t = threadIdx.x; t < 384; t += 256) wsm[t] = Wo3[t];
    if (threadIdx.x < 3) b3[threadIdx.x] = bo3[threadIdx.x];
    __syncthreads();

    const int gid = blockIdx.x * 256 + threadIdx.x;
    if (gid >= BATCH * V) return;
    const int b = gid / V;
    const int v = gid - b * V;
    const half_t* hr = h + ((size_t)b * VP + v) * 128;

    float o0 = b3[0], o1 = b3[1], o2 = b3[2];
#pragma unroll 4
    for (int c = 0; c < 128; ++c) {
        const float hv = (float)hr[c];
        o0 += hv * wsm[c * 3 + 0];
        o1 += hv * wsm[c * 3 + 1];
        o2 += hv * wsm[c * 3 + 2];
    }
    out[(size_t)gid * 3 + 0] = o0;
    out[(size_t)gid * 3 + 1] = o1;
    out[(size_t)gid * 3 + 2] = o2;
}

// ---------------------------------------------------------------------------
extern "C" void kernel_launch(void* const* d_in, const int* in_sizes, int n_in,
                              void* d_out, int out_size, void* d_ws, size_t ws_size,
                              hipStream_t stream)
{
    const float* x       = (const float*)d_in[0];
    const int*   sidx    = (const int*)  d_in[1];
    const float* W_point = (const float*)d_in[2];
    const float* res1_W  = (const float*)d_in[3];
    const float* res1_b  = (const float*)d_in[4];
    const float* W_mid   = (const float*)d_in[5];
    const float* ress_W  = (const float*)d_in[6];
    const float* ress_b  = (const float*)d_in[7];
    const float* Wo1     = (const float*)d_in[8];
    const float* bo1     = (const float*)d_in[9];
    const float* Wo2     = (const float*)d_in[10];
    const float* bo2     = (const float*)d_in[11];
    const float* Wo3     = (const float*)d_in[12];
    const float* bo3     = (const float*)d_in[13];
    float* out = (float*)d_out;

    // ---- workspace carve (bytes, 256B aligned) ----
    char* p = (char*)d_ws;
    auto alloc = [&](size_t bytes) { char* q = p; p += (bytes + 255) & ~(size_t)255; return q; };
    const size_t fs_bytes = (size_t)M_ROWS * 128 * 2;        // 6,144,512 B
    half_t* reg0 = (half_t*)alloc((size_t)M_ROWS * 512 * 2); // xh[24002][480] then h512
    half_t* pfs  = (half_t*)alloc((size_t)M_ROWS * 256 * 2);
    char*   rA   = alloc((size_t)M_ROWS * 256 * 2);          // bufA -> fsA|fsB -> h128
    char*   rB   = alloc((size_t)M_ROWS * 256 * 2);          // bufB -> tmp -> h256
    half_t* Wpt_t  = (half_t*)alloc((size_t)256 * 480 * 2);
    half_t* r1Wt   = (half_t*)alloc((size_t)2 * 256 * 4096 * 2);
    half_t* Wmid_t = (half_t*)alloc((size_t)128 * 256 * 2);
    half_t* rsWt   = (half_t*)alloc((size_t)6 * 128 * 2048 * 2);
    half_t* Wo1_t  = (half_t*)alloc((size_t)256 * 512 * 2);
    half_t* Wo2_t  = (half_t*)alloc((size_t)128 * 256 * 2);
    float*  pmax   = (float*)alloc((size_t)2 * 32 * 128 * 4);
    half_t* gfs    = (half_t*)alloc(512);

    half_t* bufA = (half_t*)rA;
    half_t* bufB = (half_t*)rB;
    half_t* fsA  = (half_t*)rA;            // [24002][128]
    half_t* fsB  = (half_t*)(rA + fs_bytes);
    half_t* tmp  = (half_t*)rB;
    half_t* h512 = reg0;
    half_t* h256 = (half_t*)rB;
    half_t* h128 = (half_t*)rA;

    const dim3 blk(256);

    // ---- prep: weight transpose+convert, x convert ----
    wcvt<<<dim3(15, 8, 1),  blk, 0, stream>>>(W_point, Wpt_t, 479, 256, 480);
    wcvt<<<dim3(128, 8, 2), blk, 0, stream>>>(res1_W, r1Wt, 4096, 256, 4096);
    wcvt<<<dim3(8, 4, 1),   blk, 0, stream>>>(W_mid, Wmid_t, 256, 128, 256);
    wcvt<<<dim3(64, 4, 6),  blk, 0, stream>>>(ress_W, rsWt, 2048, 128, 2048);
    wcvt<<<dim3(16, 8, 1),  blk, 0, stream>>>(Wo1, Wo1_t, 512, 256, 512);
    wcvt<<<dim3(8, 4, 1),   blk, 0, stream>>>(Wo2, Wo2_t, 256, 128, 256);
    cvt_x<<<M_ROWS, blk, 0, stream>>>(x, reg0);

    const int mg = (M_ROWS + 127) / 128;   // 188

    // 1. pointMLP: pfs = relu(xh @ Wpt), dummy rows zeroed
    gemm_mfma<false><<<dim3(mg, 2), blk, 0, stream>>>(
        reg0, Wpt_t, nullptr, nullptr, nullptr, pfs,
        M_ROWS, 256, 480, 0, 480, 1, 1);

    // 2. res1 conv a
    gemm_mfma<true><<<dim3(mg, 2), blk, 0, stream>>>(
        pfs, r1Wt, res1_b, nullptr, sidx, bufA,
        M_ROWS, 256, 4096, 8, 0, 1, 1);

    // 3. res1 conv b + residual(pfs)
    gemm_mfma<true><<<dim3(mg, 2), blk, 0, stream>>>(
        bufA, r1Wt + (size_t)256 * 4096, res1_b + 256, pfs, sidx, bufB,
        M_ROWS, 256, 4096, 8, 0, 1, 1);

    // 4. midDown (no bias/relu, masked)
    gemm_mfma<false><<<dim3(mg, 1), blk, 0, stream>>>(
        bufB, Wmid_t, nullptr, nullptr, nullptr, fsA,
        M_ROWS, 128, 256, 0, 256, 0, 1);

    // 5. masked global max-pool
    maxpool1<<<dim3(BATCH, 32), dim3(128), 0, stream>>>(fsA, pmax);
    maxpool2<<<dim3(BATCH), dim3(128), 0, stream>>>(pmax, gfs);

    // 6. three 128-ch residual spiral blocks
    half_t* cur = fsA;
    half_t* nxt = fsB;
    for (int i = 0; i < 3; ++i) {
        const half_t* Wa = rsWt + (size_t)(2 * i + 0) * 128 * 2048;
        const half_t* Wb = rsWt + (size_t)(2 * i + 1) * 128 * 2048;
        const float* ba = ress_b + (2 * i + 0) * 128;
        const float* bb = ress_b + (2 * i + 1) * 128;
        gemm_mfma<true><<<dim3(mg, 1), blk, 0, stream>>>(
            cur, Wa, ba, nullptr, sidx, tmp,
            M_ROWS, 128, 2048, 7, 0, 1, 1);
        gemm_mfma<true><<<dim3(mg, 1), blk, 0, stream>>>(
            tmp, Wb, bb, cur, sidx, nxt,
            M_ROWS, 128, 2048, 7, 0, 1, 1);
        half_t* t2 = cur; cur = nxt; nxt = t2;
    }
    // cur == fsB

    // 7. concat -> h512 (xh region dead)
    concat_k<<<(unsigned)(((size_t)M_ROWS * 512 + 255) / 256), blk, 0, stream>>>(
        pfs, cur, gfs, h512);

    // 8. out MLP 1 (overwrites rB; tmp dead)
    gemm_mfma<false><<<dim3(mg, 2), blk, 0, stream>>>(
        h512, Wo1_t, bo1, nullptr, nullptr, h256,
        M_ROWS, 256, 512, 0, 512, 1, 0);

    // 9. out MLP 2 (overwrites rA; fs dead)
    gemm_mfma<false><<<dim3(mg, 1), blk, 0, stream>>>(
        h256, Wo2_t, bo2, nullptr, nullptr, h128,
        M_ROWS, 128, 256, 0, 256, 1, 0);

    // 10. final 128->3 fp32
    final_k<<<(BATCH * V + 255) / 256, blk, 0, stream>>>(h128, Wo3, bo3, out);
}

// Round 5
// 685.411 us; speedup vs baseline: 4.6457x; 1.2738x over previous
//
#include <hip/hip_runtime.h>
#include <cstdint>
#include <cfloat>
#include <cstddef>

// ---------------- problem constants ----------------
constexpr int BATCH  = 2;
constexpr int V      = 12000;
constexpr int VP     = V + 1;        // 12001
constexpr int M_ROWS = BATCH * VP;   // 24002
constexpr int L_SP   = 16;

typedef _Float16 half_t;
typedef _Float16 half8 __attribute__((ext_vector_type(8)));
typedef float floatx4 __attribute__((ext_vector_type(4)));

// async global->LDS, 16B per lane (global_load_lds_dwordx4)
__device__ __forceinline__ void async_cp16(const void* g, void* l) {
    __builtin_amdgcn_global_load_lds(
        (const __attribute__((address_space(1))) unsigned int*)g,
        (__attribute__((address_space(3))) unsigned int*)l, 16, 0, 0);
}

// ---------------------------------------------------------------------------
// f16 MFMA GEMM. BM x 128 tile, BK=32, 256 thr / 4 waves in 2x2.
// BM=64: wave = 32x64 (2x4 mfma_16x16x32), grid (ceil(M/64), N/128)
// BM=32: wave = 16x64 (1x4),              grid (ceil(M/32), N/128)
// Smaller tiles -> ~750 blocks/dispatch = ~3 blocks/CU so co-resident blocks
// hide the global_load_lds drain at the barrier (random gather = long drain).
//   GATHER: A row m=(b,v) = concat_l act[b*VP + idx[v][l], 0:C], C=2^lgC
//   else  : A is [M][KA] fp16 row-major
// Wt is [N][K] fp16 (pre-transposed). Epilogue: fp32 acc + bias(f32) +
// res(f16), optional relu, rows v==VP-1 zeroed when mask. Output fp16.
// Requires: N % 128 == 0, K % 32 == 0, (GATHER) 32 | C.
// ---------------------------------------------------------------------------
template<bool GATHER, int BM>
__global__ __launch_bounds__(256, 2)
void gemm_mfma(const half_t* __restrict__ A, const half_t* __restrict__ Wt,
               const float* __restrict__ bias, const half_t* __restrict__ res,
               const int* __restrict__ idx, half_t* __restrict__ out,
               int M, int N, int K, int lgC, int KA, int relu, int mask)
{
    constexpr int AF = BM / 32;           // A fragments per wave (1 or 2)
    __shared__ half_t As[BM * 32];
    __shared__ half_t Bs[128 * 32];

    const int tid  = threadIdx.x;
    const int lane = tid & 63;
    const int w    = tid >> 6;
    const int bm   = blockIdx.x, bn = blockIdx.y;

    const int sb = (tid & 3) << 3;        // half offset within 64B row slice

    // ---- B staging: 128 rows x 64B = 512 slots, 2 per thread ----
    const int brow = tid >> 2;            // 0..63
    const half_t* w0 = Wt + (size_t)(bn * 128 + brow) * K + sb;
    const half_t* w1 = Wt + (size_t)(bn * 128 + 64 + brow) * K + sb;
    half_t* lB0 = &Bs[(size_t)tid * 8];
    half_t* lB1 = &Bs[(size_t)(tid + 256) * 8];

    // ---- A staging: BM rows x 64B = BM*4 slots ----
    const bool astage = (BM == 64) ? true : (tid < 128);   // wave-uniform
    const int arow = tid >> 2;            // valid when astage
    int m0 = bm * BM + arow; if (m0 >= M) m0 = M - 1;
    const int b0 = m0 / VP, v0 = m0 - b0 * VP;
    const half_t* a0 = GATHER ? nullptr : (A + (size_t)m0 * KA + sb);
    half_t* lA0 = &As[(size_t)tid * 8];

    // ---- compute mapping ----
    const int wm = (w >> 1) * (BM / 2);
    const int wn = (w & 1) << 6;
    const int fr = lane & 15;             // A row / B col within 16-tile
    const int qk = (lane >> 4) << 3;      // k offset = quad*8

    floatx4 acc[AF][4] = {};

    int curl = -1;
    const half_t* g0 = nullptr;
    const int Cm1 = (1 << lgC) - 1;

    const int nk = K >> 5;
    for (int t = 0; t < nk; ++t) {
        const int k0 = t << 5;
        if (astage) {
            if (GATHER) {
                const int l = k0 >> lgC;          // wave-uniform
                if (l != curl) {
                    curl = l;
                    const int j0 = idx[(v0 << 4) + l];
                    g0 = A + (((size_t)(b0 * VP + j0)) << lgC) + sb;
                }
                async_cp16(g0 + (k0 & Cm1), lA0);
            } else {
                async_cp16(a0 + k0, lA0);
            }
        }
        async_cp16(w0 + k0, lB0);
        async_cp16(w1 + k0, lB1);
        __syncthreads();   // drains vmcnt before barrier => staging visible

        half8 af[AF], bf[4];
#pragma unroll
        for (int i = 0; i < AF; ++i)
            af[i] = *(const half8*)&As[(wm + (i << 4) + fr) * 32 + qk];
#pragma unroll
        for (int j = 0; j < 4; ++j)
            bf[j] = *(const half8*)&Bs[(wn + (j << 4) + fr) * 32 + qk];
#pragma unroll
        for (int i = 0; i < AF; ++i)
#pragma unroll
            for (int j = 0; j < 4; ++j)
                acc[i][j] = __builtin_amdgcn_mfma_f32_16x16x32_f16(af[i], bf[j], acc[i][j], 0, 0, 0);
        __syncthreads();
    }

    // epilogue: C/D layout col=lane&15, row=(lane>>4)*4+reg
    const int er = (lane >> 4) << 2;
#pragma unroll
    for (int i = 0; i < AF; ++i) {
#pragma unroll
        for (int j = 0; j < 4; ++j) {
            const int n = bn * 128 + wn + (j << 4) + fr;
            const floatx4 a = acc[i][j];
#pragma unroll
            for (int r = 0; r < 4; ++r) {
                const int m = bm * BM + wm + (i << 4) + er + r;
                if (m >= M) continue;
                float val = a[r];
                if (bias) val += bias[n];
                if (res)  val += (float)res[(size_t)m * N + n];
                if (relu) val = fmaxf(val, 0.f);
                const int vv = m - (m / VP) * VP;
                if (mask && vv == VP - 1) val = 0.f;
                out[(size_t)m * N + n] = (half_t)val;
            }
        }
    }
}

// ---------------------------------------------------------------------------
// weight convert + transpose fp32 [z][K][N] -> fp16 [z][N][Kpad] (zero-pad K)
// grid (ceil(Kpad/32), ceil(N/32), z), block 256 (32x8)
// ---------------------------------------------------------------------------
__global__ void wcvt(const float* __restrict__ in, half_t* __restrict__ out,
                     int K, int N, int Kpad)
{
    __shared__ float t[32][33];
    const size_t ioff = (size_t)blockIdx.z * K * N;
    const size_t ooff = (size_t)blockIdx.z * N * Kpad;
    const int k0 = blockIdx.x * 32, n0 = blockIdx.y * 32;
    const int tx = threadIdx.x & 31, ty = threadIdx.x >> 5;
#pragma unroll
    for (int r = 0; r < 4; ++r) {
        const int k = k0 + ty + r * 8;
        t[ty + r * 8][tx] = (k < K && n0 + tx < N) ? in[ioff + (size_t)k * N + n0 + tx] : 0.f;
    }
    __syncthreads();
#pragma unroll
    for (int r = 0; r < 4; ++r) {
        const int n = n0 + ty + r * 8;
        const int k = k0 + tx;
        if (n < N && k < Kpad) out[ooff + (size_t)n * Kpad + k] = (half_t)t[tx][ty + r * 8];
    }
}

// x [B][V][479] fp32 -> xh [B*VP][480] fp16, pad col 479 and dummy rows = 0
__global__ void cvt_x(const float* __restrict__ x, half_t* __restrict__ xh)
{
    const int m = blockIdx.x;
    const int b = m / VP, v = m - b * VP;
    for (int k = threadIdx.x; k < 480; k += 256) {
        float val = (v < V && k < 479) ? x[((size_t)b * V + v) * 479 + k] : 0.f;
        xh[(size_t)m * 480 + k] = (half_t)val;
    }
}

// masked global max-pool, 2 stages. fs fp16 [B*VP][128]
__global__ void maxpool1(const half_t* __restrict__ fs, float* __restrict__ pmax)
{
    const int b = blockIdx.x, chunk = blockIdx.y;   // grid (2,32), block 128
    const int c = threadIdx.x;
    const int v0 = chunk * (V / 32);
    float m = -FLT_MAX;
    const half_t* p = fs + ((size_t)b * VP + v0) * 128 + c;
    for (int v = 0; v < V / 32; ++v) { m = fmaxf(m, (float)*p); p += 128; }
    pmax[((size_t)b * 32 + chunk) * 128 + c] = m;
}
__global__ void maxpool2(const float* __restrict__ pmax, half_t* __restrict__ gfs)
{
    const int b = blockIdx.x, c = threadIdx.x;      // grid 2, block 128
    float m = -FLT_MAX;
    for (int i = 0; i < 32; ++i) m = fmaxf(m, pmax[((size_t)b * 32 + i) * 128 + c]);
    gfs[b * 128 + c] = (half_t)m;
}

// h512[m] = [pfs(256) | fs(128) | gfs(128)*zp]  (fp16)
__global__ void concat_k(const half_t* __restrict__ pfs, const half_t* __restrict__ fs,
                         const half_t* __restrict__ gfs, half_t* __restrict__ h)
{
    const size_t i = (size_t)blockIdx.x * 256 + threadIdx.x;
    if (i >= (size_t)M_ROWS * 512) return;
    const int    n   = (int)(i & 511);
    const size_t row = i >> 9;
    const int    b   = (int)(row / VP);
    const int    v   = (int)(row - (size_t)b * VP);
    half_t val;
    if (n < 256)      val = pfs[row * 256 + n];
    else if (n < 384) val = fs[row * 128 + (n - 256)];
    else              val = (v == VP - 1) ? (half_t)0.f : gfs[b * 128 + (n - 384)];
    h[i] = val;
}

// final 128->3 (fp32 weights for accuracy), drop dummy vertex
__global__ void final_k(const half_t* __restrict__ h, const float* __restrict__ Wo3,
                        const float* __restrict__ bo3, float* __restrict__ out)
{
    __shared__ float wsm[384];
    __shared__ float b3[3];
    for (int t = threadIdx.x; t < 384; t += 256) wsm[t] = Wo3[t];
    if (threadIdx.x < 3) b3[threadIdx.x] = bo3[threadIdx.x];
    __syncthreads();

    const int gid = blockIdx.x * 256 + threadIdx.x;
    if (gid >= BATCH * V) return;
    const int b = gid / V;
    const int v = gid - b * V;
    const half_t* hr = h + ((size_t)b * VP + v) * 128;

    float o0 = b3[0], o1 = b3[1], o2 = b3[2];
#pragma unroll 4
    for (int c = 0; c < 128; ++c) {
        const float hv = (float)hr[c];
        o0 += hv * wsm[c * 3 + 0];
        o1 += hv * wsm[c * 3 + 1];
        o2 += hv * wsm[c * 3 + 2];
    }
    out[(size_t)gid * 3 + 0] = o0;
    out[(size_t)gid * 3 + 1] = o1;
    out[(size_t)gid * 3 + 2] = o2;
}

// ---------------------------------------------------------------------------
extern "C" void kernel_launch(void* const* d_in, const int* in_sizes, int n_in,
                              void* d_out, int out_size, void* d_ws, size_t ws_size,
                              hipStream_t stream)
{
    const float* x       = (const float*)d_in[0];
    const int*   sidx    = (const int*)  d_in[1];
    const float* W_point = (const float*)d_in[2];
    const float* res1_W  = (const float*)d_in[3];
    const float* res1_b  = (const float*)d_in[4];
    const float* W_mid   = (const float*)d_in[5];
    const float* ress_W  = (const float*)d_in[6];
    const float* ress_b  = (const float*)d_in[7];
    const float* Wo1     = (const float*)d_in[8];
    const float* bo1     = (const float*)d_in[9];
    const float* Wo2     = (const float*)d_in[10];
    const float* bo2     = (const float*)d_in[11];
    const float* Wo3     = (const float*)d_in[12];
    const float* bo3     = (const float*)d_in[13];
    float* out = (float*)d_out;

    // ---- workspace carve (bytes, 256B aligned) ----
    char* p = (char*)d_ws;
    auto alloc = [&](size_t bytes) { char* q = p; p += (bytes + 255) & ~(size_t)255; return q; };
    const size_t fs_bytes = (size_t)M_ROWS * 128 * 2;        // 6,144,512 B
    half_t* reg0 = (half_t*)alloc((size_t)M_ROWS * 512 * 2); // xh[24002][480] then h512
    half_t* pfs  = (half_t*)alloc((size_t)M_ROWS * 256 * 2);
    char*   rA   = alloc((size_t)M_ROWS * 256 * 2);          // bufA -> fsA|fsB -> h128
    char*   rB   = alloc((size_t)M_ROWS * 256 * 2);          // bufB -> tmp -> h256
    half_t* Wpt_t  = (half_t*)alloc((size_t)256 * 480 * 2);
    half_t* r1Wt   = (half_t*)alloc((size_t)2 * 256 * 4096 * 2);
    half_t* Wmid_t = (half_t*)alloc((size_t)128 * 256 * 2);
    half_t* rsWt   = (half_t*)alloc((size_t)6 * 128 * 2048 * 2);
    half_t* Wo1_t  = (half_t*)alloc((size_t)256 * 512 * 2);
    half_t* Wo2_t  = (half_t*)alloc((size_t)128 * 256 * 2);
    float*  pmax   = (float*)alloc((size_t)2 * 32 * 128 * 4);
    half_t* gfs    = (half_t*)alloc(512);

    half_t* bufA = (half_t*)rA;
    half_t* bufB = (half_t*)rB;
    half_t* fsA  = (half_t*)rA;            // [24002][128]
    half_t* fsB  = (half_t*)(rA + fs_bytes);
    half_t* tmp  = (half_t*)rB;
    half_t* h512 = reg0;
    half_t* h256 = (half_t*)rB;
    half_t* h128 = (half_t*)rA;

    const dim3 blk(256);

    // ---- prep: weight transpose+convert, x convert ----
    wcvt<<<dim3(15, 8, 1),  blk, 0, stream>>>(W_point, Wpt_t, 479, 256, 480);
    wcvt<<<dim3(128, 8, 2), blk, 0, stream>>>(res1_W, r1Wt, 4096, 256, 4096);
    wcvt<<<dim3(8, 4, 1),   blk, 0, stream>>>(W_mid, Wmid_t, 256, 128, 256);
    wcvt<<<dim3(64, 4, 6),  blk, 0, stream>>>(ress_W, rsWt, 2048, 128, 2048);
    wcvt<<<dim3(16, 8, 1),  blk, 0, stream>>>(Wo1, Wo1_t, 512, 256, 512);
    wcvt<<<dim3(8, 4, 1),   blk, 0, stream>>>(Wo2, Wo2_t, 256, 128, 256);
    cvt_x<<<M_ROWS, blk, 0, stream>>>(x, reg0);

    const int mg64 = (M_ROWS + 63) / 64;   // 376
    const int mg32 = (M_ROWS + 31) / 32;   // 751 -> wait: 24002/32 = 750.06 -> 751
    // 751*32 = 24032 >= 24002 OK

    // 1. pointMLP: pfs = relu(xh @ Wpt), dummy rows zeroed   [752 blocks]
    gemm_mfma<false, 64><<<dim3(mg64, 2), blk, 0, stream>>>(
        reg0, Wpt_t, nullptr, nullptr, nullptr, pfs,
        M_ROWS, 256, 480, 0, 480, 1, 1);

    // 2. res1 conv a   [752 blocks]
    gemm_mfma<true, 64><<<dim3(mg64, 2), blk, 0, stream>>>(
        pfs, r1Wt, res1_b, nullptr, sidx, bufA,
        M_ROWS, 256, 4096, 8, 0, 1, 1);

    // 3. res1 conv b + residual(pfs)   [752 blocks]
    gemm_mfma<true, 64><<<dim3(mg64, 2), blk, 0, stream>>>(
        bufA, r1Wt + (size_t)256 * 4096, res1_b + 256, pfs, sidx, bufB,
        M_ROWS, 256, 4096, 8, 0, 1, 1);

    // 4. midDown (no bias/relu, masked)   [751 blocks]
    gemm_mfma<false, 32><<<dim3(mg32, 1), blk, 0, stream>>>(
        bufB, Wmid_t, nullptr, nullptr, nullptr, fsA,
        M_ROWS, 128, 256, 0, 256, 0, 1);

    // 5. masked global max-pool
    maxpool1<<<dim3(BATCH, 32), dim3(128), 0, stream>>>(fsA, pmax);
    maxpool2<<<dim3(BATCH), dim3(128), 0, stream>>>(pmax, gfs);

    // 6. three 128-ch residual spiral blocks   [751 blocks each]
    half_t* cur = fsA;
    half_t* nxt = fsB;
    for (int i = 0; i < 3; ++i) {
        const half_t* Wa = rsWt + (size_t)(2 * i + 0) * 128 * 2048;
        const half_t* Wb = rsWt + (size_t)(2 * i + 1) * 128 * 2048;
        const float* ba = ress_b + (2 * i + 0) * 128;
        const float* bb = ress_b + (2 * i + 1) * 128;
        gemm_mfma<true, 32><<<dim3(mg32, 1), blk, 0, stream>>>(
            cur, Wa, ba, nullptr, sidx, tmp,
            M_ROWS, 128, 2048, 7, 0, 1, 1);
        gemm_mfma<true, 32><<<dim3(mg32, 1), blk, 0, stream>>>(
            tmp, Wb, bb, cur, sidx, nxt,
            M_ROWS, 128, 2048, 7, 0, 1, 1);
        half_t* t2 = cur; cur = nxt; nxt = t2;
    }
    // cur == fsB

    // 7. concat -> h512 (xh region dead)
    concat_k<<<(unsigned)(((size_t)M_ROWS * 512 + 255) / 256), blk, 0, stream>>>(
        pfs, cur, gfs, h512);

    // 8. out MLP 1 (overwrites rB; tmp dead)   [752 blocks]
    gemm_mfma<false, 64><<<dim3(mg64, 2), blk, 0, stream>>>(
        h512, Wo1_t, bo1, nullptr, nullptr, h256,
        M_ROWS, 256, 512, 0, 512, 1, 0);

    // 9. out MLP 2 (overwrites rA; fs dead)   [751 blocks]
    gemm_mfma<false, 32><<<dim3(mg32, 1), blk, 0, stream>>>(
        h256, Wo2_t, bo2, nullptr, nullptr, h128,
        M_ROWS, 128, 256, 0, 256, 1, 0);

    // 10. final 128->3 fp32
    final_k<<<(BATCH * V + 255) / 256, blk, 0, stream>>>(h128, Wo3, bo3, out);
}